// Round 4
// baseline (190.052 us; speedup 1.0000x reference)
//
#include <hip/hip_runtime.h>

// LSTM B=32768, T=50, I=2, H=32.
// R16: poly-exp2 on the packed-VALU pipe. R12-R15 (four structurally
// different kernels) all land 92-102us; wall tracks summed per-wave issue
// cycles (trans@16cyc, pk-VALU@2, MFMA~5) / 0.6. Trans = 768 of ~1300
// cyc/wave-t (40 exp + 8 rcp) = 60% -> the trans pipe occupancy is the
// bottleneck, not MFMA, not LDS, not occupancy (R14: 2x waves, same wall).
// Fix: exp2 as packed deg-5 Taylor poly (rel err 2.4e-6, far below the
// 2^-9 bf16 noise floor): round-trick n=RNE(z) via +/-1.5*2^23 (bits of
// z+M carry n -> v_lshl_add_u32 applies 2^n scale, no int cvt), Horner on
// f in [-0.5,0.5]. 22 cyc/pair vs 32 trans -> saves ~200 cyc/wave-t (15%).
// Low clamp at -120 required: zc can reach -144 and the bit-scale wraps
// (hw exp2 flushed gracefully). rcp stays trans (batched; Newton needs a
// trans seed; 4-way rcp batching overflows f32).
// Carried from R15: transposed GEMM (A=W stationary, B=h register-resident,
// k-perm ku(q*8+2p+e)=q*4+p+16e), MFMA ci-init, row-pair pk activations,
// split-precision W and h (RNE cvt_pk), scales folded (-log2e/+2log2e),
// clamps on zg and c (CL=14), batched rcp, x pre-split in 3 LDS planes.

#define TS 50
#define XSTR 51     // u32 stride of x plane rows (odd: conflict-free bcast)
#define CL 14.0f
#define WPB 4       // waves per block (independent; no barriers)

typedef short short8 __attribute__((ext_vector_type(8)));
typedef float f32x4 __attribute__((ext_vector_type(4)));
typedef float f32x2 __attribute__((ext_vector_type(2)));

__device__ __forceinline__ float fast_rcp(float x) {
    return __builtin_amdgcn_rcpf(x);
}
// packed poly exp2: 2^z per element, z clamped low at -120.
// n = RNE(z) via magic-M add/sub; bits(z+M) = 0x4B400000+n, and
// (0x4B400000<<23) mod 2^32 == 0, so bits(p) + (bits(z+M)<<23) applies 2^n.
__device__ __forceinline__ f32x2 pexp(f32x2 z) {
    const float M = 12582912.0f;          // 1.5 * 2^23
    const float c5 = 1.33335581464e-3f, c4 = 9.61812910763e-3f,
                c3 = 5.55041086648e-2f, c2 = 2.40226506959e-1f,
                c1 = 6.93147180560e-1f;
    f32x2 zc;
    zc.x = fmaxf(z.x, -120.0f);
    zc.y = fmaxf(z.y, -120.0f);
    f32x2 t = zc + M;                      // RNE to int (pk_add)
    f32x2 n = t - M;                       // n = round(z)
    f32x2 f = zc - n;                      // f in [-0.5, 0.5]
    f32x2 p = c5 * f + c4;                 // Horner deg-5 (pk_fma)
    p = p * f + c3;
    p = p * f + c2;
    p = p * f + c1;
    p = p * f + 1.0f;
    f32x2 r;
    r.x = __uint_as_float(__float_as_uint(p.x) + (__float_as_uint(t.x) << 23));
    r.y = __uint_as_float(__float_as_uint(p.y) + (__float_as_uint(t.y) << 23));
    return r;
}
__device__ __forceinline__ f32x2 prcp(f32x2 v) {           // scalar trans x2
    f32x2 r; r.x = fast_rcp(v.x); r.y = fast_rcp(v.y); return r;
}
__device__ __forceinline__ f32x2 vmin2(f32x2 v, float s) { // -> v_pk_min_f32
    f32x2 r; r.x = fminf(v.x, s); r.y = fminf(v.y, s); return r;
}
// v ~= hi + lo (bf16 each, trunc). returns (lo<<16)|hi
__device__ __forceinline__ unsigned split_pack(float v) {
    unsigned u   = __float_as_uint(v);
    float    res = v - __uint_as_float(u & 0xffff0000u);
    return __builtin_amdgcn_perm(__float_as_uint(res), u, 0x07060302u);
}
// (a & 0xffff) | (b << 16)
__device__ __forceinline__ unsigned lo_pair(unsigned a, unsigned b) {
    return __builtin_amdgcn_perm(b, a, 0x05040100u);
}
// (a >> 16) | (b & 0xffff0000)
__device__ __forceinline__ unsigned hi_pair(unsigned a, unsigned b) {
    return __builtin_amdgcn_perm(b, a, 0x07060302u);
}
// RNE split: whi = [bf16(a) | bf16(b)], wlo = [bf16(a-hi(a)) | bf16(b-hi(b))]
__device__ __forceinline__ void pack2(float a, float b,
                                      unsigned &whi, unsigned &wlo) {
    unsigned h, l;
    asm("v_cvt_pk_bf16_f32 %0, %1, %2" : "=v"(h) : "v"(a), "v"(b));
    float ra = a - __uint_as_float(h << 16);
    float rb = b - __uint_as_float(h & 0xffff0000u);
    asm("v_cvt_pk_bf16_f32 %0, %1, %2" : "=v"(l) : "v"(ra), "v"(rb));
    whi = h; wlo = l;
}

union U4S8 { uint4 v; short8 s; unsigned u[4]; };

__global__ __launch_bounds__(256, 2)
void lsnn_kernel(const float* __restrict__ x,
                 const float* __restrict__ W_ih,
                 const float* __restrict__ W_hh,
                 const float* __restrict__ b_ih,
                 const float* __restrict__ b_hh,
                 const float* __restrict__ W_out,
                 const float* __restrict__ b_out,
                 const float* __restrict__ h0,
                 const float* __restrict__ c0,
                 float* __restrict__ out)
{
    // LDS: 3 x-planes (3264 B/wave each) + out (3200 B/wave) = 52 KB/block.
    __shared__ __align__(16) unsigned xa0[WPB][16 * XSTR];
    __shared__ __align__(16) unsigned xa1[WPB][16 * XSTR];
    __shared__ __align__(16) unsigned xa2[WPB][16 * XSTR];
    __shared__ __align__(16) float    out_lds[WPB][16 * TS];

    const int  tid  = threadIdx.x;
    const int  g_w  = tid >> 6;
    const int  lane = tid & 63;
    const int  u0   = lane & 15;     // batch column (this lane's batch row)
    const int  q    = lane >> 4;     // k-block / D-row group
    const long b0   = ((long)blockIdx.x * WPB + g_w) * 16;

    unsigned* x0w = xa0[g_w];
    unsigned* x1w = xa1[g_w];
    unsigned* x2w = xa2[g_w];
    float*    ow  = out_lds[g_w];

    // ---- stage x split-packed into 3 planes (per-wave private) ----
    for (int i = lane; i < 800; i += 64) {
        int row = i / 50, t = i - row * 50;          // setup-only divide
        float2 v = *(const float2*)(x + (b0 + row) * 100 + 2 * t);
        unsigned a0 = split_pack(v.x), a1 = split_pack(v.y);
        x0w[row * XSTR + t] = a0;                    // [xh0 | xl0]
        x1w[row * XSTR + t] = a1;                    // [xh1 | xl1]
        x2w[row * XSTR + t] = lo_pair(a0, a1);       // [xh0 | xh1]
    }

    const float L2E = 1.4426950408889634f;
    const float SG  = 2.0f * L2E;

    // ---- stationary A-frags: tile n = ub*4 + gate; D-row m -> W_hh row
    //      R = gate*32 + ub*16 + m.  A word p = units (q*4+p, q*4+p+16). ----
    short8 Awh[8], Awl[8], Aci[8];
    #pragma unroll
    for (int n = 0; n < 8; ++n) {
        const int   g  = n & 3, ub = n >> 2;
        const float s  = (g == 2) ? SG : -L2E;
        const int   R  = g * 32 + ub * 16 + u0;
        const float* wr = W_hh + R * 32;
        U4S8 uh, ul;
        #pragma unroll
        for (int p = 0; p < 4; ++p) {
            unsigned p0 = split_pack(wr[q * 4 + p]      * s);
            unsigned p1 = split_pack(wr[q * 4 + p + 16] * s);
            uh.u[p] = lo_pair(p0, p1);
            ul.u[p] = hi_pair(p0, p1);
        }
        Awh[n] = uh.s;  Awl[n] = ul.s;
        U4S8 ux;
        if (q == 0) {   // ci k-rows 0..7: [wh0,wh0,wh1,wh1,wl0,wl1,bh,bl]
            unsigned s0 = split_pack(W_ih[R * 2 + 0] * s);
            unsigned s1 = split_pack(W_ih[R * 2 + 1] * s);
            unsigned sb = split_pack((b_ih[R] + b_hh[R]) * s);
            ux.u[0] = lo_pair(s0, s0);
            ux.u[1] = lo_pair(s1, s1);
            ux.u[2] = hi_pair(s0, s1);
            ux.u[3] = sb;
        } else {
            ux.u[0] = 0u; ux.u[1] = 0u; ux.u[2] = 0u; ux.u[3] = 0u;
        }
        Aci[n] = ux.s;
    }
    // ---- head A-frags: A[m][k] = W_out[ku(k)], uniform over m ----
    short8 Awoh, Awol;
    {
        U4S8 uh, ul;
        #pragma unroll
        for (int p = 0; p < 4; ++p) {
            unsigned p0 = split_pack(W_out[q * 4 + p]);
            unsigned p1 = split_pack(W_out[q * 4 + p + 16]);
            uh.u[p] = lo_pair(p0, p1);
            ul.u[p] = hi_pair(p0, p1);
        }
        Awoh = uh.s;  Awol = ul.s;
    }
    const float bout = b_out[0];

    // ---- h0 -> B-frags (register-resident recurrent state) ----
    U4S8 Bhh, Bhl;
    {
        const float* hp = h0 + (b0 + u0) * 32 + q * 4;
        float4 ha = *(const float4*)hp;
        float4 hb = *(const float4*)(hp + 16);
        pack2(ha.x, hb.x, Bhh.u[0], Bhl.u[0]);
        pack2(ha.y, hb.y, Bhh.u[1], Bhl.u[1]);
        pack2(ha.z, hb.z, Bhh.u[2], Bhl.u[2]);
        pack2(ha.w, hb.w, Bhh.u[3], Bhl.u[3]);
    }
    // ---- c0: group gi = ub*2+rr -> units ub*16+q*4+(2rr, 2rr+1) ----
    f32x2 cst2[4];
    #pragma unroll
    for (int ub = 0; ub < 2; ++ub)
        #pragma unroll
        for (int rr = 0; rr < 2; ++rr)
            cst2[ub * 2 + rr] =
                *(const f32x2*)(c0 + (b0 + u0) * 32 + ub * 16 + q * 4 + 2 * rr);

    const f32x4 ZV = {0.f, 0.f, 0.f, 0.f};
    const int xbase = u0 * XSTR;

    // ---- x prefetch for t=0 (broadcast across q) ----
    unsigned xw0 = x0w[xbase], xw1 = x1w[xbase], xw2 = x2w[xbase];

    #pragma unroll 1
    for (int t = 0; t < TS; ++t) {
        U4S8 Bx;
        Bx.u[0] = xw0;  Bx.u[1] = xw1;  Bx.u[2] = xw2;
        Bx.u[3] = 0x3f803f80u;          // [1.0, 1.0] bf16
        if (t + 1 < TS) {
            xw0 = x0w[xbase + t + 1];
            xw1 = x1w[xbase + t + 1];
            xw2 = x2w[xbase + t + 1];
        }

        // ---- output head for h_t (skip t=0): D rows all equal ----
        if (t > 0) {
            f32x4 aw = ZV;
            aw = __builtin_amdgcn_mfma_f32_16x16x32_bf16(Awoh, Bhh.s, aw, 0, 0, 0);
            aw = __builtin_amdgcn_mfma_f32_16x16x32_bf16(Awoh, Bhl.s, aw, 0, 0, 0);
            aw = __builtin_amdgcn_mfma_f32_16x16x32_bf16(Awol, Bhh.s, aw, 0, 0, 0);
            if (q == 0) ow[u0 * TS + (t - 1)] = aw[0] + bout;
        }

        // ---- gates: ci-MFMA + 3 split MFMAs per tile ----
        f32x4 acc[8];
        #pragma unroll
        for (int n = 0; n < 8; ++n)
            acc[n] = __builtin_amdgcn_mfma_f32_16x16x32_bf16(Aci[n], Bx.s, ZV, 0, 0, 0);
        #pragma unroll
        for (int n = 0; n < 8; ++n) {
            acc[n] = __builtin_amdgcn_mfma_f32_16x16x32_bf16(Awh[n], Bhh.s, acc[n], 0, 0, 0);
            acc[n] = __builtin_amdgcn_mfma_f32_16x16x32_bf16(Awh[n], Bhl.s, acc[n], 0, 0, 0);
            acc[n] = __builtin_amdgcn_mfma_f32_16x16x32_bf16(Awl[n], Bhh.s, acc[n], 0, 0, 0);
        }

        // ---- activations: 4 row-pair groups gi = ub*2+rr ----
        f32x2 Bv2[4], Cv2[4], P12[4], Ep2[4], PP2[4];
        #pragma unroll
        for (int ub = 0; ub < 2; ++ub) {
            #pragma unroll
            for (int rr = 0; rr < 2; ++rr) {
                const int gi = ub * 2 + rr, nb = ub * 4;
                f32x2 zi = {acc[nb + 0][2*rr], acc[nb + 0][2*rr + 1]};
                f32x2 zf = {acc[nb + 1][2*rr], acc[nb + 1][2*rr + 1]};
                f32x2 zg = vmin2((f32x2){acc[nb + 2][2*rr], acc[nb + 2][2*rr + 1]}, CL);
                f32x2 zo = {acc[nb + 3][2*rr], acc[nb + 3][2*rr + 1]};
                f32x2 Av = pexp(zi);          // e^{-i}
                Bv2[gi]  = pexp(zg);          // e^{2g}
                f32x2 Ev = pexp(zf);          // e^{-f}
                Cv2[gi]  = pexp(zo);          // e^{-o}
                f32x2 Ap = 1.0f + Av, Bp = 1.0f + Bv2[gi];
                Ep2[gi] = 1.0f + Ev;
                P12[gi] = Ap * Bp;
                PP2[gi] = P12[gi] * Ep2[gi];
            }
        }
        f32x2 R2[4];
        #pragma unroll
        for (int bb = 0; bb < 2; ++bb) {
            f32x2 pr = PP2[2*bb] * PP2[2*bb + 1];
            f32x2 ri = prcp(pr);
            R2[2*bb]     = PP2[2*bb + 1] * ri;
            R2[2*bb + 1] = PP2[2*bb]     * ri;
        }
        f32x2 Dv2[4], Q2[4];
        #pragma unroll
        for (int gi = 0; gi < 4; ++gi) {
            f32x2 fv = P12[gi] * R2[gi];                      // sigmoid(f)
            f32x2 ig = (Bv2[gi] - 1.0f) * (Ep2[gi] * R2[gi]); // sig(i)*tanh(g)
            f32x2 c  = fv * cst2[gi] + ig;
            cst2[gi] = c;
            f32x2 zc = vmin2(c * SG, CL);
            Dv2[gi] = pexp(zc);                               // e^{2c}
            Q2[gi]  = (1.0f + Cv2[gi]) * (1.0f + Dv2[gi]);
        }
        f32x2 RQ2[4];
        #pragma unroll
        for (int bb = 0; bb < 2; ++bb) {
            f32x2 qr = Q2[2*bb] * Q2[2*bb + 1];
            f32x2 ri = prcp(qr);
            RQ2[2*bb]     = Q2[2*bb + 1] * ri;
            RQ2[2*bb + 1] = Q2[2*bb]     * ri;
        }
        // ---- h in registers -> B-frag words [h(u), h(u+16)] ----
        float hub[2][4];
        #pragma unroll
        for (int gi = 0; gi < 4; ++gi) {
            f32x2 h2 = (Dv2[gi] - 1.0f) * RQ2[gi];            // sig(o)*tanh(c)
            hub[gi >> 1][2 * (gi & 1)]     = h2.x;
            hub[gi >> 1][2 * (gi & 1) + 1] = h2.y;
        }
        #pragma unroll
        for (int p = 0; p < 4; ++p)
            pack2(hub[0][p], hub[1][p], Bhh.u[p], Bhl.u[p]);
    }

    // ---- final head for h_50 ----
    {
        f32x4 aw = {0.f, 0.f, 0.f, 0.f};
        aw = __builtin_amdgcn_mfma_f32_16x16x32_bf16(Awoh, Bhh.s, aw, 0, 0, 0);
        aw = __builtin_amdgcn_mfma_f32_16x16x32_bf16(Awoh, Bhl.s, aw, 0, 0, 0);
        aw = __builtin_amdgcn_mfma_f32_16x16x32_bf16(Awol, Bhh.s, aw, 0, 0, 0);
        if (q == 0) ow[u0 * TS + 49] = aw[0] + bout;
    }

    // ---- coalesced flush of this wave's 800 contiguous floats ----
    {
        float4* od = (float4*)(out + b0 * 50);
        const float4* os = (const float4*)ow;
        for (int i = lane; i < 200; i += 64) od[i] = os[i];
    }
}

extern "C" void kernel_launch(void* const* d_in, const int* in_sizes, int n_in,
                              void* d_out, int out_size, void* d_ws, size_t ws_size,
                              hipStream_t stream) {
    const float* x     = (const float*)d_in[0];
    const float* W_ih  = (const float*)d_in[1];
    const float* W_hh  = (const float*)d_in[2];
    const float* b_ih  = (const float*)d_in[3];
    const float* b_hh  = (const float*)d_in[4];
    const float* W_out = (const float*)d_in[5];
    const float* b_out = (const float*)d_in[6];
    const float* h0    = (const float*)d_in[7];
    const float* c0    = (const float*)d_in[8];
    float* out = (float*)d_out;

    dim3 grid(32768 / (16 * WPB)), block(64 * WPB);
    lsnn_kernel<<<grid, block, 0, stream>>>(x, W_ih, W_hh, b_ih, b_hh,
                                            W_out, b_out, h0, c0, out);
}

// Round 5
// 151.349 us; speedup vs baseline: 1.2557x; 1.2557x over previous
//
#include <hip/hip_runtime.h>

// LSTM B=32768, T=50, I=2, H=32.
// R17 = R15 (champion, 92.9us) + fma-fusion VALU shave + anti-phase stagger.
// R16 post-mortem: poly-exp regressed 47% -> fitted issue law:
//   wall * ~0.6 = per-SIMD (2cyc * VALU_ops + 16cyc * trans_ops)
// (consistent across R12-R16). Trans term (40 exp + 8 rcp = 768 cyc/wave-t)
// is algebraically irreducible (5 exp per LSTM element); hardware v_exp_f32
// strictly beats VALU polynomials. Two levers this round:
//  (a) fma-fusion: (1+A)(1+B) -> fma(Ap,Bv,Ap); (1+Ev)R -> fma(Ev,R,R);
//      (X-1)Y -> fma(X,Y,-Y); (1+Cv)(1+Dv) -> fma(Qp,Dv,Qp). ~-20 pk/wave-t.
//  (b) anti-phase stagger: 2 co-resident waves/SIMD run identical code ->
//      trans bursts collide (busy pinned ~0.6 across R12-R15). One-time
//      s_sleep skew (~2240cyc) for one wave of each co-resident pair
//      (pair = blocks b, b+256 -> key (bid^bid>>8)&1) locks exp-burst of A
//      over algebra of B (different pipes -> skew self-sustains).
// Carried from R15: transposed GEMM (A=W stationary, B=h register-resident,
// k-perm ku(q*8+2p+e)=q*4+p+16e), MFMA ci-init, row-pair pk activations,
// split-precision W and h (RNE cvt_pk), scales folded (-log2e/+2log2e),
// clamps on zg and c (CL=14), batched rcp, x pre-split in 3 LDS planes.

#define TS 50
#define XSTR 51     // u32 stride of x plane rows (odd: conflict-free bcast)
#define CL 14.0f
#define WPB 4       // waves per block (independent; no barriers)

typedef short short8 __attribute__((ext_vector_type(8)));
typedef float f32x4 __attribute__((ext_vector_type(4)));
typedef float f32x2 __attribute__((ext_vector_type(2)));

__device__ __forceinline__ float fast_exp2(float x) {
    return __builtin_amdgcn_exp2f(x);
}
__device__ __forceinline__ float fast_rcp(float x) {
    return __builtin_amdgcn_rcpf(x);
}
__device__ __forceinline__ f32x2 pexp(f32x2 z) {           // scalar trans x2
    f32x2 r; r.x = fast_exp2(z.x); r.y = fast_exp2(z.y); return r;
}
__device__ __forceinline__ f32x2 prcp(f32x2 v) {           // scalar trans x2
    f32x2 r; r.x = fast_rcp(v.x); r.y = fast_rcp(v.y); return r;
}
__device__ __forceinline__ f32x2 vmin2(f32x2 v, float s) { // -> v_pk_min_f32
    f32x2 r; r.x = fminf(v.x, s); r.y = fminf(v.y, s); return r;
}
// v ~= hi + lo (bf16 each, trunc). returns (lo<<16)|hi
__device__ __forceinline__ unsigned split_pack(float v) {
    unsigned u   = __float_as_uint(v);
    float    res = v - __uint_as_float(u & 0xffff0000u);
    return __builtin_amdgcn_perm(__float_as_uint(res), u, 0x07060302u);
}
// (a & 0xffff) | (b << 16)
__device__ __forceinline__ unsigned lo_pair(unsigned a, unsigned b) {
    return __builtin_amdgcn_perm(b, a, 0x05040100u);
}
// (a >> 16) | (b & 0xffff0000)
__device__ __forceinline__ unsigned hi_pair(unsigned a, unsigned b) {
    return __builtin_amdgcn_perm(b, a, 0x07060302u);
}
// RNE split: whi = [bf16(a) | bf16(b)], wlo = [bf16(a-hi(a)) | bf16(b-hi(b))]
__device__ __forceinline__ void pack2(float a, float b,
                                      unsigned &whi, unsigned &wlo) {
    unsigned h, l;
    asm("v_cvt_pk_bf16_f32 %0, %1, %2" : "=v"(h) : "v"(a), "v"(b));
    float ra = a - __uint_as_float(h << 16);
    float rb = b - __uint_as_float(h & 0xffff0000u);
    asm("v_cvt_pk_bf16_f32 %0, %1, %2" : "=v"(l) : "v"(ra), "v"(rb));
    whi = h; wlo = l;
}

union U4S8 { uint4 v; short8 s; unsigned u[4]; };

__global__ __launch_bounds__(256, 2)
void lsnn_kernel(const float* __restrict__ x,
                 const float* __restrict__ W_ih,
                 const float* __restrict__ W_hh,
                 const float* __restrict__ b_ih,
                 const float* __restrict__ b_hh,
                 const float* __restrict__ W_out,
                 const float* __restrict__ b_out,
                 const float* __restrict__ h0,
                 const float* __restrict__ c0,
                 float* __restrict__ out)
{
    // LDS: 3 x-planes (3264 B/wave each) + out (3200 B/wave) = 52 KB/block.
    __shared__ __align__(16) unsigned xa0[WPB][16 * XSTR];
    __shared__ __align__(16) unsigned xa1[WPB][16 * XSTR];
    __shared__ __align__(16) unsigned xa2[WPB][16 * XSTR];
    __shared__ __align__(16) float    out_lds[WPB][16 * TS];

    const int  tid  = threadIdx.x;
    const int  g_w  = tid >> 6;
    const int  lane = tid & 63;
    const int  u0   = lane & 15;     // batch column (this lane's batch row)
    const int  q    = lane >> 4;     // k-block / D-row group
    const long b0   = ((long)blockIdx.x * WPB + g_w) * 16;

    unsigned* x0w = xa0[g_w];
    unsigned* x1w = xa1[g_w];
    unsigned* x2w = xa2[g_w];
    float*    ow  = out_lds[g_w];

    // ---- stage x split-packed into 3 planes (per-wave private) ----
    for (int i = lane; i < 800; i += 64) {
        int row = i / 50, t = i - row * 50;          // setup-only divide
        float2 v = *(const float2*)(x + (b0 + row) * 100 + 2 * t);
        unsigned a0 = split_pack(v.x), a1 = split_pack(v.y);
        x0w[row * XSTR + t] = a0;                    // [xh0 | xl0]
        x1w[row * XSTR + t] = a1;                    // [xh1 | xl1]
        x2w[row * XSTR + t] = lo_pair(a0, a1);       // [xh0 | xh1]
    }

    const float L2E = 1.4426950408889634f;
    const float SG  = 2.0f * L2E;

    // ---- stationary A-frags: tile n = ub*4 + gate; D-row m -> W_hh row
    //      R = gate*32 + ub*16 + m.  A word p = units (q*4+p, q*4+p+16). ----
    short8 Awh[8], Awl[8], Aci[8];
    #pragma unroll
    for (int n = 0; n < 8; ++n) {
        const int   g  = n & 3, ub = n >> 2;
        const float s  = (g == 2) ? SG : -L2E;
        const int   R  = g * 32 + ub * 16 + u0;
        const float* wr = W_hh + R * 32;
        U4S8 uh, ul;
        #pragma unroll
        for (int p = 0; p < 4; ++p) {
            unsigned p0 = split_pack(wr[q * 4 + p]      * s);
            unsigned p1 = split_pack(wr[q * 4 + p + 16] * s);
            uh.u[p] = lo_pair(p0, p1);
            ul.u[p] = hi_pair(p0, p1);
        }
        Awh[n] = uh.s;  Awl[n] = ul.s;
        U4S8 ux;
        if (q == 0) {   // ci k-rows 0..7: [wh0,wh0,wh1,wh1,wl0,wl1,bh,bl]
            unsigned s0 = split_pack(W_ih[R * 2 + 0] * s);
            unsigned s1 = split_pack(W_ih[R * 2 + 1] * s);
            unsigned sb = split_pack((b_ih[R] + b_hh[R]) * s);
            ux.u[0] = lo_pair(s0, s0);
            ux.u[1] = lo_pair(s1, s1);
            ux.u[2] = hi_pair(s0, s1);
            ux.u[3] = sb;
        } else {
            ux.u[0] = 0u; ux.u[1] = 0u; ux.u[2] = 0u; ux.u[3] = 0u;
        }
        Aci[n] = ux.s;
    }
    // ---- head A-frags: A[m][k] = W_out[ku(k)], uniform over m ----
    short8 Awoh, Awol;
    {
        U4S8 uh, ul;
        #pragma unroll
        for (int p = 0; p < 4; ++p) {
            unsigned p0 = split_pack(W_out[q * 4 + p]);
            unsigned p1 = split_pack(W_out[q * 4 + p + 16]);
            uh.u[p] = lo_pair(p0, p1);
            ul.u[p] = hi_pair(p0, p1);
        }
        Awoh = uh.s;  Awol = ul.s;
    }
    const float bout = b_out[0];

    // ---- h0 -> B-frags (register-resident recurrent state) ----
    U4S8 Bhh, Bhl;
    {
        const float* hp = h0 + (b0 + u0) * 32 + q * 4;
        float4 ha = *(const float4*)hp;
        float4 hb = *(const float4*)(hp + 16);
        pack2(ha.x, hb.x, Bhh.u[0], Bhl.u[0]);
        pack2(ha.y, hb.y, Bhh.u[1], Bhl.u[1]);
        pack2(ha.z, hb.z, Bhh.u[2], Bhl.u[2]);
        pack2(ha.w, hb.w, Bhh.u[3], Bhl.u[3]);
    }
    // ---- c0: group gi = ub*2+rr -> units ub*16+q*4+(2rr, 2rr+1) ----
    f32x2 cst2[4];
    #pragma unroll
    for (int ub = 0; ub < 2; ++ub)
        #pragma unroll
        for (int rr = 0; rr < 2; ++rr)
            cst2[ub * 2 + rr] =
                *(const f32x2*)(c0 + (b0 + u0) * 32 + ub * 16 + q * 4 + 2 * rr);

    const f32x4 ZV = {0.f, 0.f, 0.f, 0.f};
    const int xbase = u0 * XSTR;

    // ---- x prefetch for t=0 (broadcast across q) ----
    unsigned xw0 = x0w[xbase], xw1 = x1w[xbase], xw2 = x2w[xbase];

    // ---- anti-phase stagger: skew one wave of each co-resident pair.
    // 512 blocks / 256 CUs -> pair = (b, b+256); key differs across the
    // pair AND across adjacent blocks: ((b ^ (b>>8)) & 1).
    if (((blockIdx.x ^ (blockIdx.x >> 8)) & 1) != 0)
        __builtin_amdgcn_s_sleep(35);    // ~2240 cyc, once

    #pragma unroll 1
    for (int t = 0; t < TS; ++t) {
        U4S8 Bx;
        Bx.u[0] = xw0;  Bx.u[1] = xw1;  Bx.u[2] = xw2;
        Bx.u[3] = 0x3f803f80u;          // [1.0, 1.0] bf16
        if (t + 1 < TS) {
            xw0 = x0w[xbase + t + 1];
            xw1 = x1w[xbase + t + 1];
            xw2 = x2w[xbase + t + 1];
        }

        // ---- output head for h_t (skip t=0): D rows all equal ----
        if (t > 0) {
            f32x4 aw = ZV;
            aw = __builtin_amdgcn_mfma_f32_16x16x32_bf16(Awoh, Bhh.s, aw, 0, 0, 0);
            aw = __builtin_amdgcn_mfma_f32_16x16x32_bf16(Awoh, Bhl.s, aw, 0, 0, 0);
            aw = __builtin_amdgcn_mfma_f32_16x16x32_bf16(Awol, Bhh.s, aw, 0, 0, 0);
            if (q == 0) ow[u0 * TS + (t - 1)] = aw[0] + bout;
        }

        // ---- gates: ci-MFMA + 3 split MFMAs per tile ----
        f32x4 acc[8];
        #pragma unroll
        for (int n = 0; n < 8; ++n)
            acc[n] = __builtin_amdgcn_mfma_f32_16x16x32_bf16(Aci[n], Bx.s, ZV, 0, 0, 0);
        #pragma unroll
        for (int n = 0; n < 8; ++n) {
            acc[n] = __builtin_amdgcn_mfma_f32_16x16x32_bf16(Awh[n], Bhh.s, acc[n], 0, 0, 0);
            acc[n] = __builtin_amdgcn_mfma_f32_16x16x32_bf16(Awh[n], Bhl.s, acc[n], 0, 0, 0);
            acc[n] = __builtin_amdgcn_mfma_f32_16x16x32_bf16(Awl[n], Bhh.s, acc[n], 0, 0, 0);
        }

        // ---- activations: 4 row-pair groups gi = ub*2+rr (fma-fused) ----
        f32x2 Bv2[4], Cv2[4], Ev2[4], P12[4], PP2[4];
        #pragma unroll
        for (int ub = 0; ub < 2; ++ub) {
            #pragma unroll
            for (int rr = 0; rr < 2; ++rr) {
                const int gi = ub * 2 + rr, nb = ub * 4;
                f32x2 zi = {acc[nb + 0][2*rr], acc[nb + 0][2*rr + 1]};
                f32x2 zf = {acc[nb + 1][2*rr], acc[nb + 1][2*rr + 1]};
                f32x2 zg = vmin2((f32x2){acc[nb + 2][2*rr], acc[nb + 2][2*rr + 1]}, CL);
                f32x2 zo = {acc[nb + 3][2*rr], acc[nb + 3][2*rr + 1]};
                f32x2 Av = pexp(zi);          // e^{-i}
                Bv2[gi]  = pexp(zg);          // e^{2g}
                Ev2[gi]  = pexp(zf);          // e^{-f}
                Cv2[gi]  = pexp(zo);          // e^{-o}
                f32x2 Ap = 1.0f + Av;
                P12[gi] = Ap * Bv2[gi] + Ap;          // (1+Av)(1+Bv)
                PP2[gi] = P12[gi] * Ev2[gi] + P12[gi]; // *(1+Ev)
            }
        }
        f32x2 R2[4];
        #pragma unroll
        for (int bb = 0; bb < 2; ++bb) {
            f32x2 pr = PP2[2*bb] * PP2[2*bb + 1];
            f32x2 ri = prcp(pr);
            R2[2*bb]     = PP2[2*bb + 1] * ri;
            R2[2*bb + 1] = PP2[2*bb]     * ri;
        }
        f32x2 Dv2[4], Q2[4];
        #pragma unroll
        for (int gi = 0; gi < 4; ++gi) {
            f32x2 fv = P12[gi] * R2[gi];                     // sigmoid(f)
            f32x2 t2 = Ev2[gi] * R2[gi] + R2[gi];            // (1+Ev)*R
            f32x2 ig = Bv2[gi] * t2 - t2;                    // (Bv-1)*t2
            f32x2 c  = fv * cst2[gi] + ig;
            cst2[gi] = c;
            f32x2 zc = vmin2(c * SG, CL);
            Dv2[gi] = pexp(zc);                              // e^{2c}
            f32x2 Qp = 1.0f + Cv2[gi];
            Q2[gi]  = Qp * Dv2[gi] + Qp;                     // (1+Cv)(1+Dv)
        }
        f32x2 RQ2[4];
        #pragma unroll
        for (int bb = 0; bb < 2; ++bb) {
            f32x2 qr = Q2[2*bb] * Q2[2*bb + 1];
            f32x2 ri = prcp(qr);
            RQ2[2*bb]     = Q2[2*bb + 1] * ri;
            RQ2[2*bb + 1] = Q2[2*bb]     * ri;
        }
        // ---- h in registers -> B-frag words [h(u), h(u+16)] ----
        float hub[2][4];
        #pragma unroll
        for (int gi = 0; gi < 4; ++gi) {
            f32x2 h2 = Dv2[gi] * RQ2[gi] - RQ2[gi];          // (Dv-1)*RQ
            hub[gi >> 1][2 * (gi & 1)]     = h2.x;
            hub[gi >> 1][2 * (gi & 1) + 1] = h2.y;
        }
        #pragma unroll
        for (int p = 0; p < 4; ++p)
            pack2(hub[0][p], hub[1][p], Bhh.u[p], Bhl.u[p]);
    }

    // ---- final head for h_50 ----
    {
        f32x4 aw = {0.f, 0.f, 0.f, 0.f};
        aw = __builtin_amdgcn_mfma_f32_16x16x32_bf16(Awoh, Bhh.s, aw, 0, 0, 0);
        aw = __builtin_amdgcn_mfma_f32_16x16x32_bf16(Awoh, Bhl.s, aw, 0, 0, 0);
        aw = __builtin_amdgcn_mfma_f32_16x16x32_bf16(Awol, Bhh.s, aw, 0, 0, 0);
        if (q == 0) ow[u0 * TS + 49] = aw[0] + bout;
    }

    // ---- coalesced flush of this wave's 800 contiguous floats ----
    {
        float4* od = (float4*)(out + b0 * 50);
        const float4* os = (const float4*)ow;
        for (int i = lane; i < 200; i += 64) od[i] = os[i];
    }
}

extern "C" void kernel_launch(void* const* d_in, const int* in_sizes, int n_in,
                              void* d_out, int out_size, void* d_ws, size_t ws_size,
                              hipStream_t stream) {
    const float* x     = (const float*)d_in[0];
    const float* W_ih  = (const float*)d_in[1];
    const float* W_hh  = (const float*)d_in[2];
    const float* b_ih  = (const float*)d_in[3];
    const float* b_hh  = (const float*)d_in[4];
    const float* W_out = (const float*)d_in[5];
    const float* b_out = (const float*)d_in[6];
    const float* h0    = (const float*)d_in[7];
    const float* c0    = (const float*)d_in[8];
    float* out = (float*)d_out;

    dim3 grid(32768 / (16 * WPB)), block(64 * WPB);
    lsnn_kernel<<<grid, block, 0, stream>>>(x, W_ih, W_hh, b_ih, b_hh,
                                            W_out, b_out, h0, c0, out);
}